// Round 3
// baseline (329.055 us; speedup 1.0000x reference)
//
#include <hip/hip_runtime.h>
#include <stdint.h>

#define DD 1024      // model dim
#define NH 16        // heads
#define DHEAD 64     // head dim
#define NB 4         // batch
#define SEQ 2048     // seq len
#define MR (NB*SEQ)  // 8192 rows
#define NT (SEQ/128) // 16 Q-tiles of 128 rows

typedef __attribute__((ext_vector_type(8))) short s8v;
typedef __attribute__((ext_vector_type(4))) float f4v;

__device__ __forceinline__ unsigned short f2bf(float f) {
  union { float f; uint32_t u; } c; c.f = f;
  uint32_t u = c.u;
  u += 0x7fffu + ((u >> 16) & 1u);   // RNE
  return (unsigned short)(u >> 16);
}
__device__ __forceinline__ unsigned short f2bf_trunc(float f) {
  union { float f; uint32_t u; } c; c.f = f;
  return (unsigned short)(c.u >> 16);
}

__device__ __forceinline__ void load_lds16(const void* g, void* lds) {
  __builtin_amdgcn_global_load_lds(
      (__attribute__((address_space(1))) void*)(uintptr_t)g,
      (__attribute__((address_space(3))) void*)(uint32_t)(uintptr_t)lds,
      16, 0, 0);
}

// ---------------- fp32 -> bf16 convert, weights + activations, one launch ---
// blocks 0..2047: weights (4 x 1M); blocks 2048..14335: activations (3 x 8M)
__global__ void cvt_all(
    const float* __restrict__ w0, const float* __restrict__ w1,
    const float* __restrict__ w2, const float* __restrict__ w3,
    const float* __restrict__ a0, const float* __restrict__ a1,
    const float* __restrict__ a2,
    unsigned short* __restrict__ dw0, unsigned short* __restrict__ dw1,
    unsigned short* __restrict__ dw2, unsigned short* __restrict__ dw3,
    unsigned short* __restrict__ da0, unsigned short* __restrict__ da1,
    unsigned short* __restrict__ da2)
{
  int blk = blockIdx.x;
  const float* src;
  unsigned short* dst;
  size_t i;
  if (blk < 2048) {
    int a = blk >> 9;
    src = a == 0 ? w0 : (a == 1 ? w1 : (a == 2 ? w2 : w3));
    dst = a == 0 ? dw0 : (a == 1 ? dw1 : (a == 2 ? dw2 : dw3));
    i = (size_t)(blk & 511) * 2048 + (size_t)threadIdx.x * 8;
  } else {
    int blk2 = blk - 2048;
    int a = blk2 >> 12;
    src = a == 0 ? a0 : (a == 1 ? a1 : a2);
    dst = a == 0 ? da0 : (a == 1 ? da1 : da2);
    i = (size_t)(blk2 & 4095) * 2048 + (size_t)threadIdx.x * 8;
  }
  float4 a4 = *(const float4*)(src + i);
  float4 b4 = *(const float4*)(src + i + 4);
  union { unsigned short us[8]; uint4 u; } t;
  t.us[0] = f2bf(a4.x); t.us[1] = f2bf(a4.y); t.us[2] = f2bf(a4.z); t.us[3] = f2bf(a4.w);
  t.us[4] = f2bf(b4.x); t.us[5] = f2bf(b4.y); t.us[6] = f2bf(b4.z); t.us[7] = f2bf(b4.w);
  *(uint4*)(dst + i) = t.u;
}

// ---------------- output projection GEMM: 128x128 tiles, swizzled LDS -------
__global__ __launch_bounds__(256, 2) void gemm_bt(
    const unsigned short* __restrict__ A,
    const unsigned short* __restrict__ Bw,
    const float* __restrict__ bias,
    float* __restrict__ Cout)
{
  __shared__ __align__(16) short As[128 * 64];
  __shared__ __align__(16) short Bs[128 * 64];
  const int linear = blockIdx.y * 8 + blockIdx.x;
  const int nx = linear >> 6;        // 0..7 weight column tile
  const int my = linear & 63;        // 0..63 M tile; A co-readers share XCD
  const int tid = threadIdx.x;
  const int wave = tid >> 6, lane = tid & 63;
  const int wm = (wave >> 1) * 64, wn = (wave & 1) * 64;
  const int lr = lane & 15, lg = lane >> 4;
  const int sw = lr & 7;             // read-side swizzle key
  const unsigned short* Ab = A + (size_t)my * 128 * DD;
  const unsigned short* Bb = Bw + (size_t)nx * 128 * DD;

  f4v z = {0.f, 0.f, 0.f, 0.f};
  f4v acc[4][4];
  for (int mi = 0; mi < 4; mi++) for (int ni = 0; ni < 4; ni++) acc[mi][ni] = z;

  for (int k0 = 0; k0 < DD; k0 += 64) {
    __syncthreads();
    for (int i = 0; i < 4; i++) {
      int c = tid + i * 256;
      int row = c >> 3, pg = c & 7;
      load_lds16(Ab + (size_t)row * DD + k0 + ((pg ^ (row & 7)) << 3), As + c * 8);
    }
    for (int i = 0; i < 4; i++) {
      int c = tid + i * 256;
      int row = c >> 3, pg = c & 7;
      load_lds16(Bb + (size_t)row * DD + k0 + ((pg ^ (row & 7)) << 3), Bs + c * 8);
    }
    __syncthreads();
    for (int kk = 0; kk < 64; kk += 32) {
      int gb = kk >> 3;   // 0 or 4
      s8v af[4], bf[4];
      for (int i = 0; i < 4; i++)
        af[i] = *(const s8v*)(As + (wm + i * 16 + lr) * 64 + (((gb + lg) ^ sw) << 3));
      for (int i = 0; i < 4; i++)
        bf[i] = *(const s8v*)(Bs + (wn + i * 16 + lr) * 64 + (((gb + lg) ^ sw) << 3));
      for (int mi = 0; mi < 4; mi++)
        for (int ni = 0; ni < 4; ni++)
          acc[mi][ni] = __builtin_amdgcn_mfma_f32_16x16x32_bf16(af[mi], bf[ni], acc[mi][ni], 0, 0, 0);
    }
  }
  for (int ni = 0; ni < 4; ni++) {
    int col = nx * 128 + wn + ni * 16 + lr;
    float bv = bias[col];
    for (int mi = 0; mi < 4; mi++) {
      int row0 = my * 128 + wm + mi * 16 + lg * 4;
      for (int r = 0; r < 4; r++)
        Cout[(size_t)(row0 + r) * DD + col] = acc[mi][ni][r] + bv;
    }
  }
}

// ---------------- fused QKV projection GEMM (m97 structure) -----------------
__global__ __launch_bounds__(256, 2) void gemm_qkv(
    const unsigned short* __restrict__ qA, const unsigned short* __restrict__ kA,
    const unsigned short* __restrict__ vA,
    const unsigned short* __restrict__ wq, const unsigned short* __restrict__ wk,
    const unsigned short* __restrict__ wv,
    const float* __restrict__ bq, const float* __restrict__ bk, const float* __restrict__ bv,
    unsigned short* __restrict__ Qp, unsigned short* __restrict__ Kp,
    unsigned short* __restrict__ VpT)
{
  __shared__ __align__(16) short As[128 * 64];
  __shared__ __align__(16) short Bs[128 * 64];
  const int linear = blockIdx.y * 24 + blockIdx.x;
  const int nx  = linear / 192;        // 0..7
  const int rem = linear % 192;
  const int seg = rem >> 6;            // 0..2
  const int my  = rem & 63;            // 0..63
  const unsigned short* A  = seg == 0 ? qA : (seg == 1 ? kA : vA);
  const unsigned short* Bw = seg == 0 ? wq : (seg == 1 ? wk : wv);
  const float* bias        = seg == 0 ? bq : (seg == 1 ? bk : bv);

  const int tid = threadIdx.x;
  const int wave = tid >> 6, lane = tid & 63;
  const int wm = (wave >> 1) * 64, wn = (wave & 1) * 64;
  const int lr = lane & 15, lg = lane >> 4;
  const int sw = lr & 7;
  const unsigned short* Ab = A + (size_t)my * 128 * DD;
  const unsigned short* Bb = Bw + (size_t)nx * 128 * DD;

  f4v z = {0.f, 0.f, 0.f, 0.f};
  f4v acc[4][4];
  for (int mi = 0; mi < 4; mi++) for (int ni = 0; ni < 4; ni++) acc[mi][ni] = z;

  for (int k0 = 0; k0 < DD; k0 += 64) {
    __syncthreads();
    for (int i = 0; i < 4; i++) {
      int c = tid + i * 256;
      int row = c >> 3, pg = c & 7;
      load_lds16(Ab + (size_t)row * DD + k0 + ((pg ^ (row & 7)) << 3), As + c * 8);
    }
    for (int i = 0; i < 4; i++) {
      int c = tid + i * 256;
      int row = c >> 3, pg = c & 7;
      load_lds16(Bb + (size_t)row * DD + k0 + ((pg ^ (row & 7)) << 3), Bs + c * 8);
    }
    __syncthreads();
    for (int kk = 0; kk < 64; kk += 32) {
      int gb = kk >> 3;
      s8v af[4], bf[4];
      for (int i = 0; i < 4; i++)
        af[i] = *(const s8v*)(As + (wm + i * 16 + lr) * 64 + (((gb + lg) ^ sw) << 3));
      for (int i = 0; i < 4; i++)
        bf[i] = *(const s8v*)(Bs + (wn + i * 16 + lr) * 64 + (((gb + lg) ^ sw) << 3));
      for (int mi = 0; mi < 4; mi++)
        for (int ni = 0; ni < 4; ni++)
          acc[mi][ni] = __builtin_amdgcn_mfma_f32_16x16x32_bf16(af[mi], bf[ni], acc[mi][ni], 0, 0, 0);
    }
  }
  if (seg < 2) {
    unsigned short* Cout = seg == 0 ? Qp : Kp;
    for (int ni = 0; ni < 4; ni++) {
      int col = nx * 128 + wn + ni * 16 + lr;
      float bv = bias[col];
      for (int mi = 0; mi < 4; mi++) {
        int row0 = my * 128 + wm + mi * 16 + lg * 4;
        for (int r = 0; r < 4; r++)
          Cout[(size_t)(row0 + r) * DD + col] = f2bf(acc[mi][ni][r] + bv);
      }
    }
  } else {
    // V: transposed store VpT[bh][d][l], 4 seq-consecutive rows per 8B store
    for (int ni = 0; ni < 4; ni++) {
      int col = nx * 128 + wn + ni * 16 + lr;
      float bv = bias[col];
      int hh = col >> 6, dd = col & 63;
      for (int mi = 0; mi < 4; mi++) {
        int row0 = my * 128 + wm + mi * 16 + lg * 4;
        int bb = row0 >> 11, ll = row0 & 2047;
        uint64_t w = 0;
        for (int r = 0; r < 4; r++)
          w |= (uint64_t)f2bf(acc[mi][ni][r] + bv) << (16 * r);
        *(uint64_t*)(VpT + ((size_t)(bb * NH + hh) * 64 + dd) * SEQ + ll) = w;
      }
    }
  }
}

// ---------------- causal flash attention (paired Q-tiles, static max) -------
// Round 3: 8 waves x 16 Q-rows per 512-thread block (2x wave supply at same
// LDS); K/V tiles shared by all 8 waves; no reg-prefetch (round-2 spilled).
#define KS_STRIDE 72
#define VT_STRIDE 136
#define PS_STRIDE 72

__device__ __forceinline__ void attn_step(
    const s8v (&qf)[2], const s8v (&kf)[2][4],
    f4v (&o)[4], float (&ls)[4],
    int qbase, int colbase,
    const short* __restrict__ Vt, int vsub, short* __restrict__ Pw,
    int lr, int lg)
{
  const float csc = 0.125f * 1.44269504089f;
  const float FM = 14.0f;
  f4v zv = {0.f, 0.f, 0.f, 0.f};
  f4v s[4];
  for (int ni = 0; ni < 4; ni++) s[ni] = zv;
  __builtin_amdgcn_s_setprio(1);
  for (int ks = 0; ks < 2; ks++)
    for (int ni = 0; ni < 4; ni++)
      s[ni] = __builtin_amdgcn_mfma_f32_16x16x32_bf16(qf[ks], kf[ks][ni], s[ni], 0, 0, 0);
  __builtin_amdgcn_s_setprio(0);
  const bool diag = (colbase + 63 > qbase);
  for (int ni = 0; ni < 4; ni++)
    for (int r = 0; r < 4; r++) {
      float e = __builtin_amdgcn_exp2f(fmaf(s[ni][r], csc, -FM));
      if (diag) {
        int row = qbase + lg * 4 + r;
        int col = colbase + ni * 16 + lr;
        e = (col > row) ? 0.f : e;
      }
      ls[r] += e;
      Pw[(lg * 4 + r) * PS_STRIDE + ni * 16 + lr] = (short)f2bf_trunc(e);
    }
  for (int kc2 = 0; kc2 < 2; kc2++) {
    s8v pf, vf[4];
    pf = *(const s8v*)(Pw + lr * PS_STRIDE + kc2 * 32 + lg * 8);
    for (int ni = 0; ni < 4; ni++)
      vf[ni] = *(const s8v*)(Vt + (ni * 16 + lr) * VT_STRIDE + vsub + kc2 * 32 + lg * 8);
    __builtin_amdgcn_s_setprio(1);
    for (int ni = 0; ni < 4; ni++)
      o[ni] = __builtin_amdgcn_mfma_f32_16x16x32_bf16(pf, vf[ni], o[ni], 0, 0, 0);
    __builtin_amdgcn_s_setprio(0);
  }
}

__global__ __launch_bounds__(512, 4) void fattn(
    const unsigned short* __restrict__ Qp,
    const unsigned short* __restrict__ Kp,
    const unsigned short* __restrict__ VpT,
    unsigned short* __restrict__ Op)
{
  __shared__ __align__(16) short Ks[128 * KS_STRIDE];
  __shared__ __align__(16) short Vt[64 * VT_STRIDE];
  __shared__ __align__(16) short Ps[8 * 16 * PS_STRIDE];   // 8 waves x 16 rows
  const int tid = threadIdx.x;
  const int wave = tid >> 6, lane = tid & 63;
  const int lr = lane & 15, lg = lane >> 4;
  const int linear = blockIdx.y * 8 + blockIdx.x;
  const int xA = linear >> 6;        // 0..7 ; XCD = bh%8
  const int bh = linear & 63;        // 0..63
  const int b = bh >> 4, h = bh & 15;
  const int xB = NT - 1 - xA;
  const int qbA = xA * 128 + wave * 16;
  const int qbB = xB * 128 + wave * 16;
  const unsigned short* Qrow = Qp + ((size_t)b * SEQ) * DD + h * DHEAD;
  const unsigned short* Krow = Kp + ((size_t)b * SEQ) * DD + h * DHEAD;
  const unsigned short* VT   = VpT + (size_t)bh * 64 * SEQ;
  short* Pw = Ps + wave * (16 * PS_STRIDE);

  s8v qfA[2], qfB[2];
  for (int ks = 0; ks < 2; ks++) {
    qfA[ks] = *(const s8v*)(Qrow + (size_t)(qbA + lr) * DD + ks * 32 + lg * 8);
    qfB[ks] = *(const s8v*)(Qrow + (size_t)(qbB + lr) * DD + ks * 32 + lg * 8);
  }

  f4v zv = {0.f, 0.f, 0.f, 0.f};
  f4v oA[4], oB[4];
  float lA[4], lB[4];
  for (int r = 0; r < 4; r++) { lA[r] = 0.f; lB[r] = 0.f; }
  for (int ni = 0; ni < 4; ni++) { oA[ni] = zv; oB[ni] = zv; }

  const int npair = xB + 1;

  for (int p = 0; p < npair; p++) {
    s8v kreg[2], vreg[2];
    int krow[2], kkc[2], vd[2], vkc[2];
    for (int i = 0; i < 2; i++) {
      int c = tid + i * 512;
      krow[i] = c >> 3; kkc[i] = (c & 7) << 3;
      kreg[i] = *(const s8v*)(Krow + (size_t)(p * 128 + krow[i]) * DD + kkc[i]);
      vd[i] = c >> 4; vkc[i] = (c & 15) << 3;
      vreg[i] = *(const s8v*)(VT + (size_t)vd[i] * SEQ + p * 128 + vkc[i]);
    }
    __syncthreads();
    for (int i = 0; i < 2; i++) {
      *(s8v*)(Ks + krow[i] * KS_STRIDE + kkc[i]) = kreg[i];
      *(s8v*)(Vt + vd[i] * VT_STRIDE + vkc[i]) = vreg[i];
    }
    __syncthreads();
    for (int sub = 0; sub < 2; sub++) {
      int colbase = (2 * p + sub) * 64;
      bool actB = colbase <= qbB + 15;
      bool actA = colbase <= qbA + 15;
      if (actB || actA) {
        const short* KsSub = Ks + sub * 64 * KS_STRIDE;
        s8v kf[2][4];
        for (int ks = 0; ks < 2; ks++)
          for (int ni = 0; ni < 4; ni++)
            kf[ks][ni] = *(const s8v*)(KsSub + (ni * 16 + lr) * KS_STRIDE + ks * 32 + lg * 8);
        int vsub = sub * 64;
        if (actB) attn_step(qfB, kf, oB, lB, qbB, colbase, Vt, vsub, Pw, lr, lg);
        if (actA) attn_step(qfA, kf, oA, lA, qbA, colbase, Vt, vsub, Pw, lr, lg);
      }
    }
  }

  unsigned short* Orow = Op + ((size_t)b * SEQ) * DD + h * DHEAD;
  for (int r = 0; r < 4; r++) {
    float sA = lA[r], sB = lB[r];
    for (int d2 = 1; d2 < 16; d2 <<= 1) {
      sA += __shfl_xor(sA, d2);
      sB += __shfl_xor(sB, d2);
    }
    float invA = 1.f / sA, invB = 1.f / sB;
    size_t rowA = (size_t)qbA + lg * 4 + r;
    size_t rowB = (size_t)qbB + lg * 4 + r;
    for (int ni = 0; ni < 4; ni++) {
      Orow[rowA * DD + ni * 16 + lr] = f2bf(oA[ni][r] * invA);
      Orow[rowB * DD + ni * 16 + lr] = f2bf(oB[ni][r] * invB);
    }
  }
}

// ---------------- launcher ----------------
extern "C" void kernel_launch(void* const* d_in, const int* in_sizes, int n_in,
                              void* d_out, int out_size, void* d_ws, size_t ws_size,
                              hipStream_t stream) {
  const float* q    = (const float*)d_in[0];
  const float* k    = (const float*)d_in[1];
  const float* v    = (const float*)d_in[2];
  const float* wq_w = (const float*)d_in[3];
  const float* wq_b = (const float*)d_in[4];
  const float* wk_w = (const float*)d_in[5];
  const float* wk_b = (const float*)d_in[6];
  const float* wv_w = (const float*)d_in[7];
  const float* wv_b = (const float*)d_in[8];
  const float* wo_w = (const float*)d_in[9];
  const float* wo_b = (const float*)d_in[10];

  const size_t BIG = (size_t)MR * DD;
  const size_t WSZ = (size_t)DD * DD;
  unsigned short* p = (unsigned short*)d_ws;
  unsigned short* wqb = p; p += WSZ;
  unsigned short* wkb = p; p += WSZ;
  unsigned short* wvb = p; p += WSZ;
  unsigned short* wob = p; p += WSZ;
  unsigned short* Qp  = p; p += BIG;
  unsigned short* Kp  = p; p += BIG;
  unsigned short* VpT = p; p += BIG;   // [bh][64][SEQ]
  unsigned short* AO  = p; p += BIG;

  // bf16 activation staging, zero extra workspace:
  //  qb aliases AO  (AO only written by fattn, after gemm_qkv has consumed qb)
  //  kb/vb alias d_out (only written by gemm_bt at the very end)
  unsigned short* qb = AO;
  unsigned short* kb = (unsigned short*)d_out;
  unsigned short* vb = kb + BIG;

  cvt_all<<<dim3(14336), dim3(256), 0, stream>>>(
      wq_w, wk_w, wv_w, wo_w, q, k, v,
      wqb, wkb, wvb, wob, qb, kb, vb);

  gemm_qkv<<<dim3(24, MR / 128), dim3(256), 0, stream>>>(
      qb, kb, vb, wqb, wkb, wvb, wq_b, wk_b, wv_b, Qp, Kp, VpT);

  fattn<<<dim3(NT / 2, NB * NH), dim3(512), 0, stream>>>(Qp, Kp, VpT, AO);

  gemm_bt<<<dim3(8, MR / 128), dim3(256), 0, stream>>>(AO, wob, wo_b, (float*)d_out);

  (void)in_sizes; (void)n_in; (void)out_size; (void)ws_size;
}

// Round 4
// 302.788 us; speedup vs baseline: 1.0867x; 1.0867x over previous
//
#include <hip/hip_runtime.h>
#include <stdint.h>

#define DD 1024      // model dim
#define NH 16        // heads
#define DHEAD 64     // head dim
#define NB 4         // batch
#define SEQ 2048     // seq len
#define MR (NB*SEQ)  // 8192 rows
#define NT (SEQ/128) // 16 Q-tiles of 128 rows
#define NKT (DD/64)  // 16 K-tiles per GEMM

typedef __attribute__((ext_vector_type(8))) short s8v;
typedef __attribute__((ext_vector_type(4))) float f4v;

__device__ __forceinline__ unsigned short f2bf(float f) {
  union { float f; uint32_t u; } c; c.f = f;
  uint32_t u = c.u;
  u += 0x7fffu + ((u >> 16) & 1u);   // RNE
  return (unsigned short)(u >> 16);
}
__device__ __forceinline__ unsigned short f2bf_trunc(float f) {
  union { float f; uint32_t u; } c; c.f = f;
  return (unsigned short)(c.u >> 16);
}

__device__ __forceinline__ void load_lds16(const void* g, void* lds) {
  __builtin_amdgcn_global_load_lds(
      (__attribute__((address_space(1))) void*)(uintptr_t)g,
      (__attribute__((address_space(3))) void*)(uint32_t)(uintptr_t)lds,
      16, 0, 0);
}

// ---------------- fp32 -> bf16 convert, weights + activations, one launch ---
__global__ void cvt_all(
    const float* __restrict__ w0, const float* __restrict__ w1,
    const float* __restrict__ w2, const float* __restrict__ w3,
    const float* __restrict__ a0, const float* __restrict__ a1,
    const float* __restrict__ a2,
    unsigned short* __restrict__ dw0, unsigned short* __restrict__ dw1,
    unsigned short* __restrict__ dw2, unsigned short* __restrict__ dw3,
    unsigned short* __restrict__ da0, unsigned short* __restrict__ da1,
    unsigned short* __restrict__ da2)
{
  int blk = blockIdx.x;
  const float* src;
  unsigned short* dst;
  size_t i;
  if (blk < 2048) {
    int a = blk >> 9;
    src = a == 0 ? w0 : (a == 1 ? w1 : (a == 2 ? w2 : w3));
    dst = a == 0 ? dw0 : (a == 1 ? dw1 : (a == 2 ? dw2 : dw3));
    i = (size_t)(blk & 511) * 2048 + (size_t)threadIdx.x * 8;
  } else {
    int blk2 = blk - 2048;
    int a = blk2 >> 12;
    src = a == 0 ? a0 : (a == 1 ? a1 : a2);
    dst = a == 0 ? da0 : (a == 1 ? da1 : da2);
    i = (size_t)(blk2 & 4095) * 2048 + (size_t)threadIdx.x * 8;
  }
  float4 a4 = *(const float4*)(src + i);
  float4 b4 = *(const float4*)(src + i + 4);
  union { unsigned short us[8]; uint4 u; } t;
  t.us[0] = f2bf(a4.x); t.us[1] = f2bf(a4.y); t.us[2] = f2bf(a4.z); t.us[3] = f2bf(a4.w);
  t.us[4] = f2bf(b4.x); t.us[5] = f2bf(b4.y); t.us[6] = f2bf(b4.z); t.us[7] = f2bf(b4.w);
  *(uint4*)(dst + i) = t.u;
}

// Stage one 128x64 K-tile of A and B into LDS buffer bufi (source-permuted
// swizzle; 8 global_load_lds per thread -> vmcnt granularity = 8 per tile).
#define STAGE_AB(kt, bufi)                                                     \
  for (int i_ = 0; i_ < 4; i_++) {                                             \
    int c_ = tid + i_ * 256; int row_ = c_ >> 3, pg_ = c_ & 7;                 \
    load_lds16(Ab + (size_t)row_ * DD + (kt) * 64 + ((pg_ ^ (row_ & 7)) << 3), \
               &As[bufi][c_ * 8]);                                             \
  }                                                                            \
  for (int i_ = 0; i_ < 4; i_++) {                                             \
    int c_ = tid + i_ * 256; int row_ = c_ >> 3, pg_ = c_ & 7;                 \
    load_lds16(Bb + (size_t)row_ * DD + (kt) * 64 + ((pg_ ^ (row_ & 7)) << 3), \
               &Bs[bufi][c_ * 8]);                                             \
  }

// Pipelined K-loop body: double-buffered LDS, counted vmcnt (loads span
// barriers, never drained to 0 in main loop), raw s_barrier + sched fences.
#define GEMM_KLOOP                                                             \
  STAGE_AB(0, 0);                                                              \
  STAGE_AB(1, 1);                                                              \
  for (int t = 0; t < NKT; t++) {                                              \
    if (t < NKT - 1) asm volatile("s_waitcnt vmcnt(8)" ::: "memory");          \
    else             asm volatile("s_waitcnt vmcnt(0)" ::: "memory");          \
    __builtin_amdgcn_sched_barrier(0);                                         \
    __builtin_amdgcn_s_barrier();                                              \
    __builtin_amdgcn_sched_barrier(0);                                         \
    const short* Al = As[t & 1];                                               \
    const short* Bl = Bs[t & 1];                                               \
    for (int kk = 0; kk < 64; kk += 32) {                                      \
      int gb = kk >> 3;                                                        \
      s8v af[4], bf[4];                                                        \
      for (int i = 0; i < 4; i++)                                              \
        af[i] = *(const s8v*)(Al + (wm + i * 16 + lr) * 64 + (((gb + lg) ^ sw) << 3)); \
      for (int i = 0; i < 4; i++)                                              \
        bf[i] = *(const s8v*)(Bl + (wn + i * 16 + lr) * 64 + (((gb + lg) ^ sw) << 3)); \
      for (int mi = 0; mi < 4; mi++)                                           \
        for (int ni = 0; ni < 4; ni++)                                         \
          acc[mi][ni] = __builtin_amdgcn_mfma_f32_16x16x32_bf16(af[mi], bf[ni], acc[mi][ni], 0, 0, 0); \
    }                                                                          \
    __builtin_amdgcn_sched_barrier(0);                                         \
    __builtin_amdgcn_s_barrier();                                              \
    __builtin_amdgcn_sched_barrier(0);                                         \
    if (t + 2 < NKT) { STAGE_AB(t + 2, t & 1); }                               \
  }

// ---------------- output projection GEMM: 128x128 tiles, pipelined ---------
__global__ __launch_bounds__(256, 2) void gemm_bt(
    const unsigned short* __restrict__ A,
    const unsigned short* __restrict__ Bw,
    const float* __restrict__ bias,
    float* __restrict__ Cout)
{
  __shared__ __align__(16) short As[2][128 * 64];
  __shared__ __align__(16) short Bs[2][128 * 64];
  const int linear = blockIdx.y * 8 + blockIdx.x;
  const int nx = linear >> 6;        // 0..7 weight column tile
  const int my = linear & 63;        // 0..63 M tile; A co-readers share XCD
  const int tid = threadIdx.x;
  const int wave = tid >> 6, lane = tid & 63;
  const int wm = (wave >> 1) * 64, wn = (wave & 1) * 64;
  const int lr = lane & 15, lg = lane >> 4;
  const int sw = lr & 7;             // read-side swizzle key
  const unsigned short* Ab = A + (size_t)my * 128 * DD;
  const unsigned short* Bb = Bw + (size_t)nx * 128 * DD;

  f4v z = {0.f, 0.f, 0.f, 0.f};
  f4v acc[4][4];
  for (int mi = 0; mi < 4; mi++) for (int ni = 0; ni < 4; ni++) acc[mi][ni] = z;

  GEMM_KLOOP

  for (int ni = 0; ni < 4; ni++) {
    int col = nx * 128 + wn + ni * 16 + lr;
    float bv = bias[col];
    for (int mi = 0; mi < 4; mi++) {
      int row0 = my * 128 + wm + mi * 16 + lg * 4;
      for (int r = 0; r < 4; r++)
        Cout[(size_t)(row0 + r) * DD + col] = acc[mi][ni][r] + bv;
    }
  }
}

// ---------------- fused QKV projection GEMM, pipelined ----------------------
__global__ __launch_bounds__(256, 2) void gemm_qkv(
    const unsigned short* __restrict__ qA, const unsigned short* __restrict__ kA,
    const unsigned short* __restrict__ vA,
    const unsigned short* __restrict__ wq, const unsigned short* __restrict__ wk,
    const unsigned short* __restrict__ wv,
    const float* __restrict__ bq, const float* __restrict__ bk, const float* __restrict__ bv,
    unsigned short* __restrict__ Qp, unsigned short* __restrict__ Kp,
    unsigned short* __restrict__ VpT)
{
  __shared__ __align__(16) short As[2][128 * 64];
  __shared__ __align__(16) short Bs[2][128 * 64];
  const int linear = blockIdx.y * 24 + blockIdx.x;
  const int nx  = linear / 192;        // 0..7
  const int rem = linear % 192;
  const int seg = rem >> 6;            // 0..2
  const int my  = rem & 63;            // 0..63
  const unsigned short* A  = seg == 0 ? qA : (seg == 1 ? kA : vA);
  const unsigned short* Bw = seg == 0 ? wq : (seg == 1 ? wk : wv);
  const float* bias        = seg == 0 ? bq : (seg == 1 ? bk : bv);

  const int tid = threadIdx.x;
  const int wave = tid >> 6, lane = tid & 63;
  const int wm = (wave >> 1) * 64, wn = (wave & 1) * 64;
  const int lr = lane & 15, lg = lane >> 4;
  const int sw = lr & 7;
  const unsigned short* Ab = A + (size_t)my * 128 * DD;
  const unsigned short* Bb = Bw + (size_t)nx * 128 * DD;

  f4v z = {0.f, 0.f, 0.f, 0.f};
  f4v acc[4][4];
  for (int mi = 0; mi < 4; mi++) for (int ni = 0; ni < 4; ni++) acc[mi][ni] = z;

  GEMM_KLOOP

  if (seg < 2) {
    unsigned short* Cout = seg == 0 ? Qp : Kp;
    for (int ni = 0; ni < 4; ni++) {
      int col = nx * 128 + wn + ni * 16 + lr;
      float bv = bias[col];
      for (int mi = 0; mi < 4; mi++) {
        int row0 = my * 128 + wm + mi * 16 + lg * 4;
        for (int r = 0; r < 4; r++)
          Cout[(size_t)(row0 + r) * DD + col] = f2bf(acc[mi][ni][r] + bv);
      }
    }
  } else {
    // V: transposed store VpT[bh][d][l], 4 seq-consecutive rows per 8B store
    for (int ni = 0; ni < 4; ni++) {
      int col = nx * 128 + wn + ni * 16 + lr;
      float bv = bias[col];
      int hh = col >> 6, dd = col & 63;
      for (int mi = 0; mi < 4; mi++) {
        int row0 = my * 128 + wm + mi * 16 + lg * 4;
        int bb = row0 >> 11, ll = row0 & 2047;
        uint64_t w = 0;
        for (int r = 0; r < 4; r++)
          w |= (uint64_t)f2bf(acc[mi][ni][r] + bv) << (16 * r);
        *(uint64_t*)(VpT + ((size_t)(bb * NH + hh) * 64 + dd) * SEQ + ll) = w;
      }
    }
  }
}

// ---------------- causal flash attention (round-1 structure + setprio) ------
#define KS_STRIDE 72
#define VT_STRIDE 136
#define PS_STRIDE 72

__device__ __forceinline__ void attn_step(
    const s8v (&qf)[2][2], const s8v (&kf)[2][4],
    f4v (&o)[2][4], float (&ls)[2][4],
    int qbase, int colbase,
    const short* __restrict__ Vt, int vsub, short* __restrict__ Pw,
    int lr, int lg)
{
  const float csc = 0.125f * 1.44269504089f;
  const float FM = 14.0f;
  f4v zv = {0.f, 0.f, 0.f, 0.f};
  f4v s[2][4];
  for (int mi = 0; mi < 2; mi++) for (int ni = 0; ni < 4; ni++) s[mi][ni] = zv;
  __builtin_amdgcn_s_setprio(1);
  for (int ks = 0; ks < 2; ks++)
    for (int mi = 0; mi < 2; mi++)
      for (int ni = 0; ni < 4; ni++)
        s[mi][ni] = __builtin_amdgcn_mfma_f32_16x16x32_bf16(qf[mi][ks], kf[ks][ni], s[mi][ni], 0, 0, 0);
  __builtin_amdgcn_s_setprio(0);
  const bool diag = (colbase + 63 > qbase);
  for (int mi = 0; mi < 2; mi++)
    for (int ni = 0; ni < 4; ni++)
      for (int r = 0; r < 4; r++) {
        float e = __builtin_amdgcn_exp2f(fmaf(s[mi][ni][r], csc, -FM));
        if (diag) {
          int row = qbase + mi * 16 + lg * 4 + r;
          int col = colbase + ni * 16 + lr;
          e = (col > row) ? 0.f : e;
        }
        ls[mi][r] += e;
        Pw[(mi * 16 + lg * 4 + r) * PS_STRIDE + ni * 16 + lr] = (short)f2bf_trunc(e);
      }
  for (int kc2 = 0; kc2 < 2; kc2++) {
    s8v pf[2], vf[4];
    for (int mi = 0; mi < 2; mi++)
      pf[mi] = *(const s8v*)(Pw + (mi * 16 + lr) * PS_STRIDE + kc2 * 32 + lg * 8);
    for (int ni = 0; ni < 4; ni++)
      vf[ni] = *(const s8v*)(Vt + (ni * 16 + lr) * VT_STRIDE + vsub + kc2 * 32 + lg * 8);
    __builtin_amdgcn_s_setprio(1);
    for (int mi = 0; mi < 2; mi++)
      for (int ni = 0; ni < 4; ni++)
        o[mi][ni] = __builtin_amdgcn_mfma_f32_16x16x32_bf16(pf[mi], vf[ni], o[mi][ni], 0, 0, 0);
    __builtin_amdgcn_s_setprio(0);
  }
}

__global__ __launch_bounds__(256, 2) void fattn(
    const unsigned short* __restrict__ Qp,
    const unsigned short* __restrict__ Kp,
    const unsigned short* __restrict__ VpT,
    unsigned short* __restrict__ Op)
{
  __shared__ __align__(16) short Ks[128 * KS_STRIDE];
  __shared__ __align__(16) short Vt[64 * VT_STRIDE];
  __shared__ __align__(16) short Ps[4 * 32 * PS_STRIDE];
  const int tid = threadIdx.x;
  const int wave = tid >> 6, lane = tid & 63;
  const int lr = lane & 15, lg = lane >> 4;
  const int linear = blockIdx.y * 8 + blockIdx.x;
  const int xA = linear >> 6;        // 0..7 ; XCD = bh%8
  const int bh = linear & 63;        // 0..63
  const int b = bh >> 4, h = bh & 15;
  const int xB = NT - 1 - xA;
  const int qbA = xA * 128 + wave * 32;
  const int qbB = xB * 128 + wave * 32;
  const unsigned short* Qrow = Qp + ((size_t)b * SEQ) * DD + h * DHEAD;
  const unsigned short* Krow = Kp + ((size_t)b * SEQ) * DD + h * DHEAD;
  const unsigned short* VT   = VpT + (size_t)bh * 64 * SEQ;
  short* Pw = Ps + wave * (32 * PS_STRIDE);

  s8v qfA[2][2], qfB[2][2];
  for (int mi = 0; mi < 2; mi++)
    for (int ks = 0; ks < 2; ks++) {
      qfA[mi][ks] = *(const s8v*)(Qrow + (size_t)(qbA + mi * 16 + lr) * DD + ks * 32 + lg * 8);
      qfB[mi][ks] = *(const s8v*)(Qrow + (size_t)(qbB + mi * 16 + lr) * DD + ks * 32 + lg * 8);
    }

  f4v zv = {0.f, 0.f, 0.f, 0.f};
  f4v oA[2][4], oB[2][4];
  float lA[2][4], lB[2][4];
  for (int mi = 0; mi < 2; mi++)
    for (int r = 0; r < 4; r++) { lA[mi][r] = 0.f; lB[mi][r] = 0.f; }
  for (int mi = 0; mi < 2; mi++)
    for (int ni = 0; ni < 4; ni++) { oA[mi][ni] = zv; oB[mi][ni] = zv; }

  const int npair = xB + 1;

  for (int p = 0; p < npair; p++) {
    s8v kreg[4], vreg[4];
    int krow[4], kkc[4], vd[4], vkc[4];
    for (int i = 0; i < 4; i++) {
      int c = tid + i * 256;
      krow[i] = c >> 3; kkc[i] = (c & 7) << 3;
      kreg[i] = *(const s8v*)(Krow + (size_t)(p * 128 + krow[i]) * DD + kkc[i]);
      vd[i] = c >> 4; vkc[i] = (c & 15) << 3;
      vreg[i] = *(const s8v*)(VT + (size_t)vd[i] * SEQ + p * 128 + vkc[i]);
    }
    __syncthreads();
    for (int i = 0; i < 4; i++) {
      *(s8v*)(Ks + krow[i] * KS_STRIDE + kkc[i]) = kreg[i];
      *(s8v*)(Vt + vd[i] * VT_STRIDE + vkc[i]) = vreg[i];
    }
    __syncthreads();
    for (int sub = 0; sub < 2; sub++) {
      int colbase = (2 * p + sub) * 64;
      bool actB = colbase <= qbB + 31;
      bool actA = colbase <= qbA + 31;
      if (actB || actA) {
        const short* KsSub = Ks + sub * 64 * KS_STRIDE;
        s8v kf[2][4];
        for (int ks = 0; ks < 2; ks++)
          for (int ni = 0; ni < 4; ni++)
            kf[ks][ni] = *(const s8v*)(KsSub + (ni * 16 + lr) * KS_STRIDE + ks * 32 + lg * 8);
        int vsub = sub * 64;
        if (actB) attn_step(qfB, kf, oB, lB, qbB, colbase, Vt, vsub, Pw, lr, lg);
        if (actA) attn_step(qfA, kf, oA, lA, qbA, colbase, Vt, vsub, Pw, lr, lg);
      }
    }
  }

  unsigned short* Orow = Op + ((size_t)b * SEQ) * DD + h * DHEAD;
  for (int mi = 0; mi < 2; mi++)
    for (int r = 0; r < 4; r++) {
      float sA = lA[mi][r], sB = lB[mi][r];
      for (int d2 = 1; d2 < 16; d2 <<= 1) {
        sA += __shfl_xor(sA, d2);
        sB += __shfl_xor(sB, d2);
      }
      float invA = 1.f / sA, invB = 1.f / sB;
      size_t rowA = (size_t)qbA + mi * 16 + lg * 4 + r;
      size_t rowB = (size_t)qbB + mi * 16 + lg * 4 + r;
      for (int ni = 0; ni < 4; ni++) {
        Orow[rowA * DD + ni * 16 + lr] = f2bf(oA[mi][ni][r] * invA);
        Orow[rowB * DD + ni * 16 + lr] = f2bf(oB[mi][ni][r] * invB);
      }
    }
}

// ---------------- launcher ----------------
extern "C" void kernel_launch(void* const* d_in, const int* in_sizes, int n_in,
                              void* d_out, int out_size, void* d_ws, size_t ws_size,
                              hipStream_t stream) {
  const float* q    = (const float*)d_in[0];
  const float* k    = (const float*)d_in[1];
  const float* v    = (const float*)d_in[2];
  const float* wq_w = (const float*)d_in[3];
  const float* wq_b = (const float*)d_in[4];
  const float* wk_w = (const float*)d_in[5];
  const float* wk_b = (const float*)d_in[6];
  const float* wv_w = (const float*)d_in[7];
  const float* wv_b = (const float*)d_in[8];
  const float* wo_w = (const float*)d_in[9];
  const float* wo_b = (const float*)d_in[10];

  const size_t BIG = (size_t)MR * DD;
  const size_t WSZ = (size_t)DD * DD;
  unsigned short* p = (unsigned short*)d_ws;
  unsigned short* wqb = p; p += WSZ;
  unsigned short* wkb = p; p += WSZ;
  unsigned short* wvb = p; p += WSZ;
  unsigned short* wob = p; p += WSZ;
  unsigned short* Qp  = p; p += BIG;
  unsigned short* Kp  = p; p += BIG;
  unsigned short* VpT = p; p += BIG;   // [bh][64][SEQ]
  unsigned short* AO  = p; p += BIG;

  // bf16 activation staging, zero extra workspace:
  //  qb aliases AO  (AO only written by fattn, after gemm_qkv has consumed qb)
  //  kb/vb alias d_out (only written by gemm_bt at the very end)
  unsigned short* qb = AO;
  unsigned short* kb = (unsigned short*)d_out;
  unsigned short* vb = kb + BIG;

  cvt_all<<<dim3(14336), dim3(256), 0, stream>>>(
      wq_w, wk_w, wv_w, wo_w, q, k, v,
      wqb, wkb, wvb, wob, qb, kb, vb);

  gemm_qkv<<<dim3(24, MR / 128), dim3(256), 0, stream>>>(
      qb, kb, vb, wqb, wkb, wvb, wq_b, wk_b, wv_b, Qp, Kp, VpT);

  fattn<<<dim3(NT / 2, NB * NH), dim3(256), 0, stream>>>(Qp, Kp, VpT, AO);

  gemm_bt<<<dim3(8, MR / 128), dim3(256), 0, stream>>>(AO, wob, wo_b, (float*)d_out);

  (void)in_sizes; (void)n_in; (void)out_size; (void)ws_size;
}